// Round 6
// baseline (269.789 us; speedup 1.0000x reference)
//
#include <hip/hip_runtime.h>
#include <stdint.h>

// QuantizedConv2d int8 implicit GEMM via MFMA i32_32x32x32_i8.
// N=32, C_in=128, H=W=56, C_out=256, 3x3, pad 1, stride 1.
// Output int8 values stored as int32 (harness reads integer outputs as np.int32).
//
// R6: 32x32x32 MFMA (longer instrs, 4404 TOPS), B-LDS 36 KB -> 4 blocks/CU
// (2x occupancy vs R5), XCD-swizzled bid so the 8 co-blocks sharing an M-range
// run consecutively on one XCD (A stays hot in that XCD's L2).

#define NB 32
#define CI 128
#define HH 56
#define WW 56
#define CO 256
#define SPA (HH * WW)            // 3136; 64 | 3136 -> wave tiles never cross n
#define XP_BYTES (NB * SPA * CI) // 12845056
#define BP_BYTES (8 * 36 * 1024) // 294912

typedef int v4i  __attribute__((ext_vector_type(4)));
typedef int v16i __attribute__((ext_vector_type(16)));

// ---- prep: blocks [0,1792): pack x; blocks [1792,2048): pack w + BG ----
__global__ __launch_bounds__(256) void prep_kernel(
    const int* __restrict__ x, const int* __restrict__ wgt,
    const int* __restrict__ bias, const int* __restrict__ zpi,
    int8_t* __restrict__ xp, int8_t* __restrict__ bp, int* __restrict__ BG)
{
    __shared__ int sm[1824];
    const int tid = threadIdx.x, bid = blockIdx.x;

    if (bid < HH * NB) {
        // ---- pack x: int32 NCHW -> int8 NHWC, dword-packed transpose ----
        const int h = bid % HH, n = bid / HH;
        if (bid == 0 && tid < 32) ((int*)(xp + XP_BYTES))[tid] = 0;  // zero page
        #pragma unroll
        for (int it = 0; it < 7; ++it) {
            int j = tid + it * 256;                 // 1792 = 128 ci x 14 w4
            int ci = j / 14, w4 = j - ci * 14;
            const v4i v = *(const v4i*)(x + ((n * CI + ci) * HH + h) * WW + w4 * 4);
            int p = (v.x & 255) | ((v.y & 255) << 8) | ((v.z & 255) << 16) | (v.w << 24);
            sm[w4 * 130 + ci] = p;
        }
        __syncthreads();
        int* xpd = (int*)xp + (n * HH + h) * (WW * CI / 4);
        #pragma unroll
        for (int it = 0; it < 7; ++it) {
            int o = tid + it * 256;                 // o = w*32 + ci4
            int w = o >> 5, ci4 = o & 31;
            int base = (w >> 2) * 130 + ci4 * 4;
            int sh = (w & 3) * 8;
            int d0 = sm[base], d1 = sm[base + 1], d2 = sm[base + 2], d3 = sm[base + 3];
            xpd[o] = ((d0 >> sh) & 0xff) | (((d1 >> sh) & 0xff) << 8) |
                     (((d2 >> sh) & 0xff) << 16) | ((d3 >> sh) << 24);
        }
    } else {
        // ---- pack w for one co + BG[co][9] ----
        const int co = bid - HH * NB;
        const int co32 = co >> 5, col = co & 31;
        for (int j = tid; j < 1152; j += 256) sm[j] = wgt[co * 1152 + j];  // [ci][9]
        __syncthreads();
        for (int j = tid; j < 288; j += 256) {      // 9t x 4kc x 2half x 4j4
            int j4 = j & 3, half = (j >> 2) & 1, kc = (j >> 3) & 3, t = j >> 5;
            int ci = kc * 32 + half * 16 + j4 * 4;
            int b0 = sm[(ci + 0) * 9 + t] & 255, b1 = sm[(ci + 1) * 9 + t] & 255;
            int b2 = sm[(ci + 2) * 9 + t] & 255, b3 = sm[(ci + 3) * 9 + t];
            ((int*)bp)[((co32 * 36 + t * 4 + kc) * 64 + half * 32 + col) * 4 + j4] =
                b0 | (b1 << 8) | (b2 << 16) | (b3 << 24);
        }
        if (tid < 9) {                              // per-tap weight sums
            int s = 0;
            for (int ci = 0; ci < CI; ++ci) s += sm[ci * 9 + tid];
            sm[1152 + tid] = s;
        }
        __syncthreads();
        if (tid < 9) {                              // border-class -> BG
            int hc = tid / 3, wc = tid - hc * 3;
            int dlo = (hc == 0) ? 1 : 0, dhi = (hc == 2) ? 1 : 2;
            int clo = (wc == 0) ? 1 : 0, chi = (wc == 2) ? 1 : 2;
            int s = 0;
            for (int dr = dlo; dr <= dhi; ++dr)
                for (int dc = clo; dc <= chi; ++dc) s += sm[1152 + dr * 3 + dc];
            BG[co * 9 + tid] = bias[co] - (*zpi) * s;
        }
    }
}

// ---- main: block = 256 M x 32 co, 4 waves of 64 M x 32 co; barrier-free K ----
__global__ __launch_bounds__(256, 4) void qconv_mfma(
    const int8_t* __restrict__ xp, const int8_t* __restrict__ bp,
    const int* __restrict__ BG,
    const float* __restrict__ si, const float* __restrict__ sw,
    const float* __restrict__ so, const int* __restrict__ zpo,
    int* __restrict__ out)
{
    const int tid  = threadIdx.x, lane = tid & 63, wid = tid >> 6;
    const int half = lane >> 5, l32 = lane & 31;
    // XCD swizzle: bid&7 = XCD (round-robin); 8 consecutive same-XCD blocks
    // share an M-range and sweep the 8 co-blocks -> A hot in that XCD's L2.
    const int bid  = blockIdx.x;
    const int xcd  = bid & 7, co32 = (bid >> 3) & 7, mi = bid >> 6;
    const int m_idx  = xcd * 49 + mi;               // 0..391
    const int mbase  = m_idx * 256 + wid * 64;
    const int cobase = co32 * 32;

    __shared__ char smem[36 * 1024];        // B: 36 x 1KB units; epilogue aliases

    #pragma unroll
    for (int k = 0; k < 9; ++k) {           // stage B once (9 KB per wave)
        const int u = wid + 4 * k;          // 0..35
        __builtin_amdgcn_global_load_lds(
            (const __attribute__((address_space(1))) void*)
                (bp + ((co32 * 36 + u) << 10) + lane * 16),
            (__attribute__((address_space(3))) void*)(smem + (u << 10)),
            16, 0, 0);
    }

    const int nS   = mbase / SPA;           // wave-uniform (64 | 3136)
    const int remS = mbase - nS * SPA;
    int r[2], hh[2], ww[2];
    #pragma unroll
    for (int mt = 0; mt < 2; ++mt) {        // A row: m = lane&31 within 32-tile
        const int rm = remS + mt * 32 + l32;
        hh[mt] = rm / WW; ww[mt] = rm - hh[mt] * WW;
        r[mt]  = mbase + mt * 32 + l32;
    }
    const int klo = half * 16;              // A k-offset: k = half*16 + j

    v16i acc[2];
    #pragma unroll
    for (int mt = 0; mt < 2; ++mt)
        #pragma unroll
        for (int i = 0; i < 16; ++i) acc[mt][i] = 0;

    __syncthreads();                        // B staged (barrier drains vmcnt)

    #pragma unroll
    for (int t = 0; t < 9; ++t) {
        const int dr = t / 3, dc = t - dr * 3;
        v4i aC[2][4];
        #pragma unroll
        for (int mt = 0; mt < 2; ++mt) {
            const bool v = ((unsigned)(hh[mt] + dr - 1) < HH) &&
                           ((unsigned)(ww[mt] + dc - 1) < WW);
            const int o = v ? ((r[mt] + (dr - 1) * WW + (dc - 1)) << 7) + klo
                            : XP_BYTES;     // 128-B zero page
            #pragma unroll
            for (int kc = 0; kc < 4; ++kc)
                aC[mt][kc] = *(const v4i*)(xp + o + kc * 32);
        }
        #pragma unroll
        for (int kc = 0; kc < 4; ++kc) {
            v4i b = *(const v4i*)(smem + ((t * 4 + kc) << 10) + lane * 16);
            acc[0] = __builtin_amdgcn_mfma_i32_32x32x32_i8(aC[0][kc], b, acc[0], 0, 0, 0);
            acc[1] = __builtin_amdgcn_mfma_i32_32x32x32_i8(aC[1][kc], b, acc[1], 0, 0, 0);
        }
    }

    // ---- epilogue: requant + LDS transpose (aliased onto dead B) ----
    const float rs = (*si) * (*sw) / (*so);
    const float zo = (float)(*zpo);

    __syncthreads();                        // all waves done reading B
    int* lt = (int*)smem + wid * (32 * 66); // [co_local][m_local], stride 66

    #pragma unroll
    for (int mt = 0; mt < 2; ++mt) {
        #pragma unroll
        for (int g = 0; g < 4; ++g) {
            const int rowb = mt * 32 + g * 8 + half * 4;  // C/D row group
            v4i vv;
            #pragma unroll
            for (int i = 0; i < 4; ++i) {
                const int rm = remS + rowb + i;
                const int h2 = rm / WW, w2 = rm - h2 * WW;
                const int hc = (h2 == 0) ? 0 : ((h2 == HH - 1) ? 2 : 1);
                const int wc = (w2 == 0) ? 0 : ((w2 == WW - 1) ? 2 : 1);
                const int co = cobase + l32;              // C/D col = lane&31
                int a = acc[mt][g * 4 + i] + BG[co * 9 + hc * 3 + wc];
                float y = rintf((float)a * rs + zo);
                y = fminf(fmaxf(y, -128.f), 127.f);
                vv[i] = (int)y;
            }
            *(v4i*)(lt + l32 * 66 + rowb) = vv;
        }
    }
    // same-wave ds_write -> ds_read: in-order, no barrier

    #pragma unroll
    for (int cc = 0; cc < 8; ++cc) {
        const int col = cc * 4 + (lane >> 4);             // co_local 0..31
        const int m4  = (lane & 15) * 4;                  // 16 lanes x 16 B = 256-B run
        v4i v = *(const v4i*)(lt + col * 66 + m4);
        const int oidx = (nS * CO + cobase + col) * SPA + remS + m4;
        *(v4i*)(out + oidx) = v;
    }
}

extern "C" void kernel_launch(void* const* d_in, const int* in_sizes, int n_in,
                              void* d_out, int out_size, void* d_ws, size_t ws_size,
                              hipStream_t stream) {
    const int*   x    = (const int*)d_in[0];
    const int*   wgt  = (const int*)d_in[1];
    const int*   bias = (const int*)d_in[2];
    const float* si   = (const float*)d_in[3];
    const float* sw   = (const float*)d_in[4];
    const float* so   = (const float*)d_in[5];
    const int*   zpi  = (const int*)d_in[6];
    const int*   zpo  = (const int*)d_in[7];
    int* out = (int*)d_out;

    int8_t* xp = (int8_t*)d_ws;                 // + 128-B zero page
    int8_t* bp = xp + XP_BYTES + 128;
    int*    bg = (int*)(bp + BP_BYTES);

    prep_kernel<<<HH * NB + CO, 256, 0, stream>>>(x, wgt, bias, zpi, xp, bp, bg);
    qconv_mfma<<<100352 / 256 * 8, 256, 0, stream>>>(
        xp, bp, bg, si, sw, so, zpo, out);
}